// Round 8
// baseline (133.404 us; speedup 1.0000x reference)
//
#include <hip/hip_runtime.h>
#include <stdint.h>
#include <stddef.h>

#define SS 1024
#define BB 16
#define DD 512
#define HH 8
#define DHH 64

typedef __attribute__((ext_vector_type(8))) short bf16x8;
typedef __attribute__((ext_vector_type(4))) float f32x4;
typedef __attribute__((ext_vector_type(16))) float f32x16;
typedef __attribute__((ext_vector_type(4))) float float4v;
typedef __attribute__((ext_vector_type(4))) unsigned short us4;
typedef __attribute__((ext_vector_type(4))) unsigned int uint4v;

__device__ __forceinline__ unsigned short f2bf(float f) {
  union { float f; unsigned int u; } v; v.f = f;
  unsigned int x = v.u;
  return (unsigned short)((x + 0x7FFFu + ((x >> 16) & 1u)) >> 16);
}

// async global->LDS, 16B per lane; LDS dest is wave-uniform base (+lane*16 implicit)
#define GLDS16(dst, src)                                                                  \
  __builtin_amdgcn_global_load_lds(                                                      \
      (const __attribute__((address_space(1))) unsigned int*)(const void*)(src),         \
      (__attribute__((address_space(3))) unsigned int*)(void*)(dst), 16, 0, 0)

// ---------------- Kernel A: f32 -> bf16 conversion (x and the 3 weight stacks) --------
// wq is pre-scaled by log2(e)/4 so attn gets u = e^{2x} = exp2(sc) directly (x = s/8).
__global__ void cvt_kernel(const float* __restrict__ x,
                           const float* __restrict__ wq,
                           const float* __restrict__ wk,
                           const float* __restrict__ wv,
                           unsigned short* __restrict__ xb,
                           unsigned short* __restrict__ wb) {
  const int i = blockIdx.x * 256 + threadIdx.x;   // one float4 per thread
  const int n_x4 = (SS * BB * DD) / 4;            // 2,097,152
  if (i < n_x4) {
    float4v v = ((const float4v*)x)[i];
    us4 o;
    o[0] = f2bf(v[0]); o[1] = f2bf(v[1]); o[2] = f2bf(v[2]); o[3] = f2bf(v[3]);
    ((us4*)xb)[i] = o;
  } else {
    const int j = i - n_x4;            // 0..196607
    const int sel = j >> 16;           // which weight (65536 float4 each)
    const int off4 = j & 65535;
    const float* wsrc = (sel == 0) ? wq : ((sel == 1) ? wk : wv);
    const float scale = (sel == 0) ? 0.36067376022224085f : 1.0f;
    float4v v = ((const float4v*)wsrc)[off4];
    us4 o;
    o[0] = f2bf(v[0] * scale); o[1] = f2bf(v[1] * scale);
    o[2] = f2bf(v[2] * scale); o[3] = f2bf(v[3] * scale);
    ((us4*)wb)[(sel << 16) + off4] = o;
  }
}

// ---------------- Kernel B: projection GEMM  Y[s,f] = sum_d x[s,b,d] * w[f,d] ---------
// grid: (8 M-tiles, 4 N-tiles, 48 = b*3+wsel). 128x128 tile, BK=32, 4 waves of 64x64.
// Outputs: wsel 0/1 -> q/k as [bh][s][e] bf16 ; wsel 2 -> vT as [bh][e][s] bf16.
__global__ __launch_bounds__(256) void proj_kernel(
    const unsigned short* __restrict__ xb,
    const unsigned short* __restrict__ wb,
    unsigned short* __restrict__ qb,
    unsigned short* __restrict__ kb,
    unsigned short* __restrict__ vt) {
  const int bm = blockIdx.x * 128;
  const int bn = blockIdx.y * 128;
  const int b = blockIdx.z / 3;
  const int wsel = blockIdx.z % 3;

  __shared__ unsigned short At[128 * 32];
  __shared__ unsigned short Bt[128 * 32];
  __shared__ unsigned short OT[4][64 * 72];   // per-wave 64x64 transpose pad +8

  const int tid = threadIdx.x;
  const int w = tid >> 6;
  const int lane = tid & 63;

  const unsigned short* wptr = wb + wsel * (512 * DD);

  f32x4 acc[4][4];
#pragma unroll
  for (int mi = 0; mi < 4; ++mi)
#pragma unroll
    for (int ni = 0; ni < 4; ++ni) acc[mi][ni] = (f32x4){0.f, 0.f, 0.f, 0.f};

  const int m0 = (w & 1) * 64;
  const int n0 = (w >> 1) * 64;

  for (int kt = 0; kt < 16; ++kt) {
#pragma unroll
    for (int i = 0; i < 2; ++i) {
      const int idx8 = i * 256 + tid;        // 0..511 : r = idx8/4, c8 = idx8%4
      const int r = idx8 >> 2;
      const int c8 = idx8 & 3;
      GLDS16(&At[(i * 256 + w * 64) * 8],
             xb + (size_t)(bm + r) * (BB * DD) + b * DD + kt * 32 + c8 * 8);
      GLDS16(&Bt[(i * 256 + w * 64) * 8],
             wptr + (size_t)(bn + r) * DD + kt * 32 + c8 * 8);
    }
    __syncthreads();
    bf16x8 af[4], bfr[4];
#pragma unroll
    for (int mi = 0; mi < 4; ++mi)
      af[mi] = *(const bf16x8*)&At[(m0 + mi * 16 + (lane & 15)) * 32 + (lane >> 4) * 8];
#pragma unroll
    for (int ni = 0; ni < 4; ++ni)
      bfr[ni] = *(const bf16x8*)&Bt[(n0 + ni * 16 + (lane & 15)) * 32 + (lane >> 4) * 8];
#pragma unroll
    for (int mi = 0; mi < 4; ++mi)
#pragma unroll
      for (int ni = 0; ni < 4; ++ni)
        acc[mi][ni] =
            __builtin_amdgcn_mfma_f32_16x16x32_bf16(af[mi], bfr[ni], acc[mi][ni], 0, 0, 0);
    __syncthreads();
  }

  // epilogue: per-wave LDS transpose, then coalesced 16B global stores
  const int h = (bn + n0) >> 6;                 // wave's 64 features = exactly one head
  unsigned short* OTw = &OT[w][0];
  if (wsel != 2) {
    // OT[row=s_local][col=e]
#pragma unroll
    for (int mi = 0; mi < 4; ++mi)
#pragma unroll
      for (int ni = 0; ni < 4; ++ni)
#pragma unroll
        for (int j = 0; j < 4; ++j)
          OTw[(mi * 16 + (lane >> 4) * 4 + j) * 72 + ni * 16 + (lane & 15)] =
              f2bf(acc[mi][ni][j]);
  } else {
    // OT[row=e][col=s_local]  (transposed store, 4 consecutive s pack to 8B)
#pragma unroll
    for (int mi = 0; mi < 4; ++mi)
#pragma unroll
      for (int ni = 0; ni < 4; ++ni) {
        us4 pk;
#pragma unroll
        for (int j = 0; j < 4; ++j) pk[j] = f2bf(acc[mi][ni][j]);
        *(us4*)&OTw[(ni * 16 + (lane & 15)) * 72 + mi * 16 + (lane >> 4) * 4] = pk;
      }
  }
  unsigned short* gout = (wsel == 0) ? qb : ((wsel == 1) ? kb : vt);
#pragma unroll
  for (int pass = 0; pass < 8; ++pass) {
    const int row = pass * 8 + (lane >> 3);
    bf16x8 vrow = *(const bf16x8*)&OTw[row * 72 + (lane & 7) * 8];
    size_t dst;
    if (wsel != 2)
      dst = ((size_t)(b * HH + h) * SS + (size_t)(bm + m0 + row)) * DHH + (lane & 7) * 8;
    else
      dst = ((size_t)(b * HH + h) * DHH + (size_t)row) * SS + (bm + m0) + (lane & 7) * 8;
    *(bf16x8*)&gout[dst] = vrow;
  }
}

// ---------------- Kernel C: fused attention, v8 ---------------------------------------
// R7 base + (1) T14 async-STAGE: global->reg loads issued at kt top, swizzled
// ds_write_b128 just before the barrier (vmcnt wait off the barrier path);
// (2) Pade(2,2) softmax: e^tanh = (19u^2+22u+7)/(7u^2+22u+19), u=exp2(sc) clamped,
// 1.25 trans/elem (was 2.25). Mask read raw (0/1) and folded as a multiply.
__global__ __launch_bounds__(256, 4) void attn_kernel(
    const unsigned short* __restrict__ qb,
    const unsigned short* __restrict__ kb,
    const unsigned short* __restrict__ vt,
    const float* __restrict__ mask,
    float* __restrict__ out) {
  // bijective XCD decode: 1024 blocks = 8 XCDs x (16 bh x 8 qt)
  const int id = blockIdx.x;
  const int xcd = id & 7;
  const int slot = id >> 3;
  const int bh = xcd * 16 + (slot >> 3);
  const int qt = slot & 7;
  const int b = bh >> 3;
  const int h = bh & 7;
  const int tid = threadIdx.x;
  const int w = tid >> 6;
  const int lane = tid & 63;
  const int l31 = lane & 31;
  const int hi32 = lane >> 5;
  // sigma: swap bits 2/3 of l31 -> C-tile regs r=0..7 hold keys 8*hi+0..7 (A-frag layout)
  const int sl = (l31 & 0x13) | ((l31 & 4) << 1) | ((l31 & 8) >> 1);

  __shared__ unsigned short Ks[2][64 * 64];  // [key][dh], 128B rows, XOR-swizzled
  __shared__ unsigned short Vs[2][64 * 64];  // [e][key],  128B rows, XOR-swizzled
  __shared__ float rs_s[4][32];              // per-wave rowsum reciprocals

  const size_t base_qk = (size_t)bh * SS * DHH;
  const int q0 = qt * 128 + w * 32;

  // Q B-frags: aq[ks]: q-row = q0+l31, dh = ks*16 + hi32*8 .. +8
  bf16x8 aq[4];
  {
    const unsigned short* qp = qb + base_qk + (size_t)(q0 + l31) * DHH + hi32 * 8;
    aq[0] = *(const bf16x8*)(qp);
    aq[1] = *(const bf16x8*)(qp + 16);
    aq[2] = *(const bf16x8*)(qp + 32);
    aq[3] = *(const bf16x8*)(qp + 48);
  }

  // T14 staging: global src LINEAR; ds_write at XOR-swizzled offset (same LDS image
  // as the old pre-swizzled-source + linear GLDS16 — verified identical).
  const int srow = w * 16 + (lane >> 3);              // rows srow and srow+8
  const unsigned short* kg = kb + base_qk + (size_t)srow * DHH + (lane & 7) * 8;
  const unsigned short* vg =
      vt + (size_t)bh * DHH * SS + (size_t)srow * SS + (lane & 7) * 8;
  const int lofs = srow * 128 + (((lane & 7) ^ (lane >> 3)) << 4);  // swizzled byte off

  f32x16 accO[2];
#pragma unroll
  for (int n = 0; n < 2; ++n)
#pragma unroll
    for (int i = 0; i < 16; ++i) accO[n][i] = 0.f;
  float rs = 0.f;
  const float* mrow = mask + b * SS;

  // prologue: stage tile 0
  {
    uint4v a0 = *(const uint4v*)kg;
    uint4v a1 = *(const uint4v*)(kg + 8 * DHH);
    uint4v a2 = *(const uint4v*)vg;
    uint4v a3 = *(const uint4v*)(vg + 8 * SS);
    *(uint4v*)((char*)&Ks[0][0] + lofs) = a0;
    *(uint4v*)((char*)&Ks[0][0] + lofs + 1024) = a1;
    *(uint4v*)((char*)&Vs[0][0] + lofs) = a2;
    *(uint4v*)((char*)&Vs[0][0] + lofs + 1024) = a3;
  }
  __syncthreads();

  int buf = 0;
  for (int kt = 0; kt < 16; ++kt) {
    // T14 phase A: issue next tile's global loads (latency hides under compute)
    uint4v nk0, nk1, nv0, nv1;
    if (kt < 15) {
      const unsigned short* kgn = kg + (size_t)(kt + 1) * (64 * DHH);
      const unsigned short* vgn = vg + (size_t)(kt + 1) * 64;
      nk0 = *(const uint4v*)kgn;
      nk1 = *(const uint4v*)(kgn + 8 * DHH);
      nv0 = *(const uint4v*)vgn;
      nv1 = *(const uint4v*)(vgn + 8 * SS);
    }
    const char* Kb = (const char*)&Ks[buf][0];
    const char* Vb = (const char*)&Vs[buf][0];

#pragma unroll
    for (int T = 0; T < 2; ++T) {            // two 32-key tiles per kt
      const int krow = T * 32 + sl;          // sigma-permuted key row
      const int ksw = (krow & 7) << 4;
      f32x16 sc = {};
      __builtin_amdgcn_s_setprio(1);
#pragma unroll
      for (int ks = 0; ks < 4; ++ks) {
        bf16x8 kf = *(const bf16x8*)(Kb + krow * 128 + ((ks * 32 + hi32 * 16) ^ ksw));
        sc = __builtin_amdgcn_mfma_f32_32x32x16_bf16(kf, aq[ks], sc, 0, 0, 0);
      }
      __builtin_amdgcn_s_setprio(0);
      // Pade softmax: u = exp2(sc) (= e^{2x}); p = me*(19u^2+22u+7)/(7u^2+22u+19).
      // Clamp u<=16384 so the quad-batched den product stays finite in f32
      // (tanh err at clamp: 1.2e-4, negligible).
      unsigned int pu[16];
#pragma unroll
      for (int g = 0; g < 4; ++g) {
        // keys for regs r=g*4+i: kt*64 + T*32 + (g>>1)*16 + hi32*8 + (g&1)*4 + i
        float4v mv = *(const float4v*)&mrow[kt * 64 + T * 32 + (g >> 1) * 16 +
                                            hi32 * 8 + (g & 1) * 4];
        float u0 = __builtin_fminf(__builtin_amdgcn_exp2f(sc[g * 4 + 0]), 16384.f);
        float u1 = __builtin_fminf(__builtin_amdgcn_exp2f(sc[g * 4 + 1]), 16384.f);
        float u2 = __builtin_fminf(__builtin_amdgcn_exp2f(sc[g * 4 + 2]), 16384.f);
        float u3 = __builtin_fminf(__builtin_amdgcn_exp2f(sc[g * 4 + 3]), 16384.f);
        float n0 = __builtin_fmaf(__builtin_fmaf(19.f, u0, 22.f), u0, 7.f);
        float n1 = __builtin_fmaf(__builtin_fmaf(19.f, u1, 22.f), u1, 7.f);
        float n2 = __builtin_fmaf(__builtin_fmaf(19.f, u2, 22.f), u2, 7.f);
        float n3 = __builtin_fmaf(__builtin_fmaf(19.f, u3, 22.f), u3, 7.f);
        float d0 = __builtin_fmaf(__builtin_fmaf(7.f, u0, 22.f), u0, 19.f);
        float d1 = __builtin_fmaf(__builtin_fmaf(7.f, u1, 22.f), u1, 19.f);
        float d2 = __builtin_fmaf(__builtin_fmaf(7.f, u2, 22.f), u2, 19.f);
        float d3 = __builtin_fmaf(__builtin_fmaf(7.f, u3, 22.f), u3, 19.f);
        float p01 = d0 * d1, p23 = d2 * d3;
        float rq = __builtin_amdgcn_rcpf(p01 * p23);
        float r01 = p23 * rq, r23 = p01 * rq;
        float qr0 = d1 * r01, qr1 = d0 * r01, qr2 = d3 * r23, qr3 = d2 * r23;
        float p0 = (mv[0] * n0) * qr0;
        float p1 = (mv[1] * n1) * qr1;
        float p2 = (mv[2] * n2) * qr2;
        float p3 = (mv[3] * n3) * qr3;
        rs += p0; rs += p1; rs += p2; rs += p3;
        union { float f; unsigned int u; } c0, c1, c2, c3;
        c0.f = p0; c1.f = p1; c2.f = p2; c3.f = p3;
        pu[g * 4 + 0] = c0.u; pu[g * 4 + 1] = c1.u;
        pu[g * 4 + 2] = c2.u; pu[g * 4 + 3] = c3.u;
      }
      // pack to bf16 pairs (truncate; bias cancels in p*v / sum(p)) — A-frag laid already
      union { unsigned int u[4]; bf16x8 v; } f0, f1;
#pragma unroll
      for (int m = 0; m < 4; ++m) {
        f0.u[m] = __builtin_amdgcn_perm(pu[2 * m + 1], pu[2 * m], 0x07060302u);
        f1.u[m] = __builtin_amdgcn_perm(pu[8 + 2 * m + 1], pu[8 + 2 * m], 0x07060302u);
      }
      // PV: A = P frags (keys T*32+0..15 / +16..31), B = V from swizzled LDS
      __builtin_amdgcn_s_setprio(1);
#pragma unroll
      for (int n = 0; n < 2; ++n) {
        const int vrow = n * 32 + l31;
        const int vsw = (vrow & 7) << 4;
        bf16x8 bv0 = *(const bf16x8*)(Vb + vrow * 128 + (((T * 2 + 0) * 32 + hi32 * 16) ^ vsw));
        bf16x8 bv1 = *(const bf16x8*)(Vb + vrow * 128 + (((T * 2 + 1) * 32 + hi32 * 16) ^ vsw));
        accO[n] = __builtin_amdgcn_mfma_f32_32x32x16_bf16(f0.v, bv0, accO[n], 0, 0, 0);
        accO[n] = __builtin_amdgcn_mfma_f32_32x32x16_bf16(f1.v, bv1, accO[n], 0, 0, 0);
      }
      __builtin_amdgcn_s_setprio(0);
    }

    // T14 phase B: vmcnt-wait + swizzled ds_write of next tile (into buf^1)
    if (kt < 15) {
      char* Kn = (char*)&Ks[buf ^ 1][0];
      char* Vn = (char*)&Vs[buf ^ 1][0];
      *(uint4v*)(Kn + lofs) = nk0;
      *(uint4v*)(Kn + lofs + 1024) = nk1;
      *(uint4v*)(Vn + lofs) = nv0;
      *(uint4v*)(Vn + lofs + 1024) = nv1;
    }
    __syncthreads();   // orders LDS: next tile written, current tile done being read
    buf ^= 1;
  }

  // rowsum: lane's rs covers its hi32-half of keys for q=l31; combine + invert
  rs += __shfl_xor(rs, 32, 64);
  if (hi32 == 0) rs_s[w][l31] = __builtin_amdgcn_rcpf(rs);
  float4v ri[4];
#pragma unroll
  for (int g = 0; g < 4; ++g) ri[g] = *(const float4v*)&rs_s[w][g * 8 + hi32 * 4];

#pragma unroll
  for (int n = 0; n < 2; ++n)
#pragma unroll
    for (int g = 0; g < 4; ++g)
#pragma unroll
      for (int i = 0; i < 4; ++i) {
        const int qrow = q0 + g * 8 + hi32 * 4 + i;
        out[((size_t)qrow * BB + b) * DD + h * DHH + n * 32 + l31] =
            accO[n][g * 4 + i] * ri[g][i];
      }
}

extern "C" void kernel_launch(void* const* d_in, const int* in_sizes, int n_in,
                              void* d_out, int out_size, void* d_ws, size_t ws_size,
                              hipStream_t stream) {
  const float* x = (const float*)d_in[0];
  const float* mask = (const float*)d_in[1];
  const float* wq = (const float*)d_in[2];
  const float* wk = (const float*)d_in[3];
  const float* wv = (const float*)d_in[4];
  float* out = (float*)d_out;

  char* ws = (char*)d_ws;
  unsigned short* xb = (unsigned short*)(ws);                         // 16 MB
  unsigned short* wb = (unsigned short*)(ws + (16ull << 20));         // 1.5 MB
  unsigned short* qb = (unsigned short*)(ws + (18ull << 20));         // 16 MB
  unsigned short* kb = (unsigned short*)(ws + (34ull << 20));         // 16 MB
  unsigned short* vt = (unsigned short*)(ws + (50ull << 20));         // 16 MB -> 66 MB

  cvt_kernel<<<dim3(8960), 256, 0, stream>>>(x, wq, wk, wv, xb, wb);
  proj_kernel<<<dim3(8, 4, 48), 256, 0, stream>>>(xb, wb, qb, kb, vt);
  attn_kernel<<<dim3(1024), 256, 0, stream>>>(qb, kb, vt, mask, out);
}